// Round 19
// baseline (40.215 us; speedup 1.0000x reference)
//
#include <hip/hip_runtime.h>
#include <math.h>

#define ROWS_TOTAL 8192
#define KDIM 4096
#define NJ 25
#define BM 32            // rows per block: two 16-row tiles per wave
#define NSW 16           // K-steps of 32 per wave (8 waves x 512 k)

typedef __attribute__((ext_vector_type(8))) short bf16x8;
typedef __attribute__((ext_vector_type(4))) float f32x4;

// gfx950 packed f32->bf16 (RNE); dst.lo=bf16(lo), dst.hi=bf16(hi).
// asm cvt_pk beat pure-C f2bf here (R13=41.0 vs R15=45.3).
__device__ __forceinline__ unsigned cvt_pk_bf16(float lo, float hi) {
    unsigned r;
    asm("v_cvt_pk_bf16_f32 %0, %1, %2" : "=v"(r) : "v"(lo), "v"(hi));
    return r;
}

union BF { uint4 u4; bf16x8 h; };

__device__ __forceinline__ float sigmoidf_(float z) {
    return 1.f / (1.f + __expf(-z));
}

// ------------------------------------------------------------------
// Kernel 0: pack B = (rmsw * phi) into MFMA-fragment order, bf16.
// 128 blocks x 128 threads (one frag per thread). (unchanged)
// ------------------------------------------------------------------
__global__ __launch_bounds__(128) void mhc_pack(
    const float* __restrict__ rmsw,
    const float* __restrict__ phi_pre,
    const float* __restrict__ phi_post,
    const float* __restrict__ phi_res,
    uint4* __restrict__ packed)
{
    const int fid = blockIdx.x * 128 + threadIdx.x;   // 0..16383
    const int s   = fid >> 7;
    const int n   = (fid >> 6) & 1;
    const int ln  = fid & 63;
    const int col = n * 16 + (ln & 15);
    const int kl  = s * 32 + 8 * (ln >> 4);
    float v[8];
    #pragma unroll
    for (int j = 0; j < 8; ++j) {
        const int k = kl + j;
        float vv = 0.f;
        if (col < 4)       vv = rmsw[k] * phi_pre[k * 4 + col];
        else if (col < 8)  vv = rmsw[k] * phi_post[k * 4 + (col - 4)];
        else if (col < 24) vv = rmsw[k] * phi_res[k * 16 + (col - 8)];
        v[j] = vv;
    }
    uint4 pk;
    pk.x = cvt_pk_bf16(v[0], v[1]);
    pk.y = cvt_pk_bf16(v[2], v[3]);
    pk.z = cvt_pk_bf16(v[4], v[5]);
    pk.w = cvt_pk_bf16(v[6], v[7]);
    packed[fid] = pk;
}

// ------------------------------------------------------------------
// Kernel 1: full-K fused projection + epilogue. 256 blocks x 512 thr.
// BM=32: wave w covers k in [512w, 512w+512) for TWO 16-row tiles.
// R19 change vs R18: unroll 2 -> 4. At 1 block/CU (8 waves) the
// latency-BW product needs ~17-22KB outstanding per CU; unroll 2 kept
// only ~1.5KB in flight. unroll 4 doubles in-flight loads; VGPR may
// rise to ~130-160 which costs nothing at 2 waves/SIMD occupancy.
// No launch-bounds min-waves (R1/R7/R14 trap).
// ------------------------------------------------------------------
__global__ __launch_bounds__(512) void mhc_full(
    const float* __restrict__ x,
    const uint4* __restrict__ packed,
    const float* __restrict__ b_pre,
    const float* __restrict__ b_post,
    const float* __restrict__ b_res,
    const float* __restrict__ a_pre,
    const float* __restrict__ a_post,
    const float* __restrict__ a_res,
    float* __restrict__ out)
{
    __shared__ float red[8 * 2 * 9 * 64];   // 36.9 KB

    const int t    = threadIdx.x;
    const int wave = t >> 6;               // 0..7 = k-slice (512 k each)
    const int lane = t & 63;
    const int g    = blockIdx.x;           // row group 0..255

    const int row0 = g * BM + (lane & 15);
    const float* xr0 = x + (size_t)row0 * KDIM + wave * 512 + 8 * (lane >> 4);
    const float* xr1 = xr0 + (size_t)16 * KDIM;
    const uint4* pb = packed + (wave * NSW) * (2 * 64);

    f32x4 acc00 = {0.f, 0.f, 0.f, 0.f};
    f32x4 acc01 = {0.f, 0.f, 0.f, 0.f};
    f32x4 acc10 = {0.f, 0.f, 0.f, 0.f};
    f32x4 acc11 = {0.f, 0.f, 0.f, 0.f};
    float ssqt0 = 0.f, ssqt1 = 0.f;

    #pragma unroll 4
    for (int s = 0; s < NSW; ++s) {
        const float4 p0 = *(const float4*)(xr0 + 32 * s);
        const float4 p1 = *(const float4*)(xr0 + 32 * s + 4);
        const float4 q0 = *(const float4*)(xr1 + 32 * s);
        const float4 q1 = *(const float4*)(xr1 + 32 * s + 4);
        BF b0, b1;
        b0.u4 = pb[(s * 2 + 0) * 64 + lane];
        b1.u4 = pb[(s * 2 + 1) * 64 + lane];

        ssqt0 = fmaf(p0.x, p0.x, ssqt0);
        ssqt0 = fmaf(p0.y, p0.y, ssqt0);
        ssqt0 = fmaf(p0.z, p0.z, ssqt0);
        ssqt0 = fmaf(p0.w, p0.w, ssqt0);
        ssqt0 = fmaf(p1.x, p1.x, ssqt0);
        ssqt0 = fmaf(p1.y, p1.y, ssqt0);
        ssqt0 = fmaf(p1.z, p1.z, ssqt0);
        ssqt0 = fmaf(p1.w, p1.w, ssqt0);
        ssqt1 = fmaf(q0.x, q0.x, ssqt1);
        ssqt1 = fmaf(q0.y, q0.y, ssqt1);
        ssqt1 = fmaf(q0.z, q0.z, ssqt1);
        ssqt1 = fmaf(q0.w, q0.w, ssqt1);
        ssqt1 = fmaf(q1.x, q1.x, ssqt1);
        ssqt1 = fmaf(q1.y, q1.y, ssqt1);
        ssqt1 = fmaf(q1.z, q1.z, ssqt1);
        ssqt1 = fmaf(q1.w, q1.w, ssqt1);

        BF af0, af1;
        af0.u4.x = cvt_pk_bf16(p0.x, p0.y);
        af0.u4.y = cvt_pk_bf16(p0.z, p0.w);
        af0.u4.z = cvt_pk_bf16(p1.x, p1.y);
        af0.u4.w = cvt_pk_bf16(p1.z, p1.w);
        af1.u4.x = cvt_pk_bf16(q0.x, q0.y);
        af1.u4.y = cvt_pk_bf16(q0.z, q0.w);
        af1.u4.z = cvt_pk_bf16(q1.x, q1.y);
        af1.u4.w = cvt_pk_bf16(q1.z, q1.w);

        acc00 = __builtin_amdgcn_mfma_f32_16x16x32_bf16(af0.h, b0.h, acc00, 0, 0, 0);
        acc01 = __builtin_amdgcn_mfma_f32_16x16x32_bf16(af0.h, b1.h, acc01, 0, 0, 0);
        acc10 = __builtin_amdgcn_mfma_f32_16x16x32_bf16(af1.h, b0.h, acc10, 0, 0, 0);
        acc11 = __builtin_amdgcn_mfma_f32_16x16x32_bf16(af1.h, b1.h, acc11, 0, 0, 0);
    }

    // fold the 4 k-offset lane groups (same row across l>>4)
    ssqt0 += __shfl_xor(ssqt0, 16);
    ssqt0 += __shfl_xor(ssqt0, 32);
    ssqt1 += __shfl_xor(ssqt1, 16);
    ssqt1 += __shfl_xor(ssqt1, 32);

    // ---- dump per-wave partials: red[wave][tile][j(9)][lane] ----
    float* myred = red + wave * 1152;
    #pragma unroll
    for (int r = 0; r < 4; ++r) myred[r * 64 + lane] = acc00[r];
    #pragma unroll
    for (int r = 0; r < 4; ++r) myred[(4 + r) * 64 + lane] = acc01[r];
    myred[8 * 64 + lane] = ssqt0;
    #pragma unroll
    for (int r = 0; r < 4; ++r) myred[576 + r * 64 + lane] = acc10[r];
    #pragma unroll
    for (int r = 0; r < 4; ++r) myred[576 + (4 + r) * 64 + lane] = acc11[r];
    myred[576 + 8 * 64 + lane] = ssqt1;
    __syncthreads();

    // ---- reduce 8 wave-slices into slot 0 (1152 sums, 512 threads) ----
    for (int i = t; i < 1152; i += 512) {
        float s = red[i];
        #pragma unroll
        for (int q = 1; q < 8; ++q)
            s += red[q * 1152 + i];
        red[i] = s;
    }
    __syncthreads();

    // ---- epilogue: 32 rows x 16 cells = all 512 threads ----
    // value(local row lr, col c) = red[tile*576 + jslot*64 + li],
    //   jslot = (lr&3) + (c<16 ? 0 : 4), li = (c&15) + 16*(lr>>2).
    {
        const int rr   = t >> 4;          // block row 0..31
        const int cell = t & 15;          // res cell i*4+jc
        const int tile = rr >> 4;
        const int lr   = rr & 15;
        const int gr   = g * BM + rr;
        const float* rb = red + tile * 576;

        const float scale = rsqrtf(rb[8 * 64 + lr] * (1.0f / KDIM) + 1e-6f);
        const int li = 16 * (lr >> 2);
        const int j0 = lr & 3;

        if (cell < 4) {
            const float v = rb[j0 * 64 + li + cell];
            out[gr * 4 + cell] = sigmoidf_(fmaf(a_pre[0] * scale, v, b_pre[cell]));
        } else if (cell < 8) {
            const float v = rb[j0 * 64 + li + cell];
            out[32768 + gr * 4 + (cell - 4)] =
                2.f * sigmoidf_(fmaf(a_post[0] * scale, v, b_post[cell - 4]));
        }

        // res column 8+cell (acc*0 holds cols 0-15, acc*1 cols 16-31)
        const int col   = 8 + cell;
        const int jslot = j0 + (col < 16 ? 0 : 4);
        const float v   = rb[jslot * 64 + (col & 15) + li];
        float m = __expf(fmaf(a_res[0] * scale, v, b_res[cell]));

        for (int it = 0; it < 20; ++it) {
            float s = m + __shfl_xor(m, 1);       // row sum over jc
            s += __shfl_xor(s, 2);
            m /= s;
            float c = m + __shfl_xor(m, 4);       // col sum over i
            c += __shfl_xor(c, 8);
            m /= c;
        }
        out[65536 + gr * 16 + cell] = m;
    }
}

extern "C" void kernel_launch(void* const* d_in, const int* in_sizes, int n_in,
                              void* d_out, int out_size, void* d_ws, size_t ws_size,
                              hipStream_t stream) {
    const float* x      = (const float*)d_in[0];
    const float* rmsw   = (const float*)d_in[1];
    const float* ppre   = (const float*)d_in[2];
    const float* ppost  = (const float*)d_in[3];
    const float* pres   = (const float*)d_in[4];
    const float* b_pre  = (const float*)d_in[5];
    const float* b_post = (const float*)d_in[6];
    const float* b_res  = (const float*)d_in[7];
    const float* a_pre  = (const float*)d_in[8];
    const float* a_post = (const float*)d_in[9];
    const float* a_res  = (const float*)d_in[10];
    float* out = (float*)d_out;

    uint4* packed = (uint4*)d_ws;   // 256 KB
    hipLaunchKernelGGL(mhc_pack, dim3(128), dim3(128), 0, stream,
                       rmsw, ppre, ppost, pres, packed);
    hipLaunchKernelGGL(mhc_full, dim3(256), dim3(512), 0, stream,
                       x, packed, b_pre, b_post, b_res,
                       a_pre, a_post, a_res, out);
}

// Round 20
// 37.880 us; speedup vs baseline: 1.0616x; 1.0616x over previous
//
#include <hip/hip_runtime.h>
#include <math.h>

#define ROWS_TOTAL 8192
#define KDIM 4096
#define NJ 25
#define BM 32            // rows per block: two 16-row tiles per wave
#define NSW 16           // K-steps of 32 per wave (8 waves x 512 k)

typedef __attribute__((ext_vector_type(8))) short bf16x8;
typedef __attribute__((ext_vector_type(4))) float f32x4;

// gfx950 packed f32->bf16 (RNE); dst.lo=bf16(lo), dst.hi=bf16(hi).
// asm cvt_pk beat pure-C f2bf here (R13=41.0 vs R15=45.3).
__device__ __forceinline__ unsigned cvt_pk_bf16(float lo, float hi) {
    unsigned r;
    asm("v_cvt_pk_bf16_f32 %0, %1, %2" : "=v"(r) : "v"(lo), "v"(hi));
    return r;
}

union BF { uint4 u4; bf16x8 h; };

__device__ __forceinline__ float sigmoidf_(float z) {
    return 1.f / (1.f + __expf(-z));
}

// ------------------------------------------------------------------
// Kernel 0: pack B = (rmsw * phi) into MFMA-fragment order, bf16.
// 128 blocks x 128 threads (one frag per thread).
// ------------------------------------------------------------------
__global__ __launch_bounds__(128) void mhc_pack(
    const float* __restrict__ rmsw,
    const float* __restrict__ phi_pre,
    const float* __restrict__ phi_post,
    const float* __restrict__ phi_res,
    uint4* __restrict__ packed)
{
    const int fid = blockIdx.x * 128 + threadIdx.x;   // 0..16383
    const int s   = fid >> 7;
    const int n   = (fid >> 6) & 1;
    const int ln  = fid & 63;
    const int col = n * 16 + (ln & 15);
    const int kl  = s * 32 + 8 * (ln >> 4);
    float v[8];
    #pragma unroll
    for (int j = 0; j < 8; ++j) {
        const int k = kl + j;
        float vv = 0.f;
        if (col < 4)       vv = rmsw[k] * phi_pre[k * 4 + col];
        else if (col < 8)  vv = rmsw[k] * phi_post[k * 4 + (col - 4)];
        else if (col < 24) vv = rmsw[k] * phi_res[k * 16 + (col - 8)];
        v[j] = vv;
    }
    uint4 pk;
    pk.x = cvt_pk_bf16(v[0], v[1]);
    pk.y = cvt_pk_bf16(v[2], v[3]);
    pk.z = cvt_pk_bf16(v[4], v[5]);
    pk.w = cvt_pk_bf16(v[6], v[7]);
    packed[fid] = pk;
}

// ------------------------------------------------------------------
// Kernel 1: full-K fused projection + epilogue. 256 blocks x 512 thr.
// BM=32, unroll 2 -- the measured ILP/TLP optimum (R18=37.4):
//   unroll 2 keeps VGPR<=128 -> 2 blocks/CU (16 waves);
//   unroll 4 (R19=40.2) pushed VGPR past 128 -> 1 block/CU, net loss.
// Wave w covers k in [512w, 512w+512) for TWO 16-row tiles against
// the same B fragments. Cross-wave reduce in LDS (36.9 KB), then
// 32 rows x 16 cells = 512 threads run per-cell Sinkhorn.
// No launch-bounds min-waves (R1/R7/R14 trap).
// ------------------------------------------------------------------
__global__ __launch_bounds__(512) void mhc_full(
    const float* __restrict__ x,
    const uint4* __restrict__ packed,
    const float* __restrict__ b_pre,
    const float* __restrict__ b_post,
    const float* __restrict__ b_res,
    const float* __restrict__ a_pre,
    const float* __restrict__ a_post,
    const float* __restrict__ a_res,
    float* __restrict__ out)
{
    __shared__ float red[8 * 2 * 9 * 64];   // 36.9 KB

    const int t    = threadIdx.x;
    const int wave = t >> 6;               // 0..7 = k-slice (512 k each)
    const int lane = t & 63;
    const int g    = blockIdx.x;           // row group 0..255

    const int row0 = g * BM + (lane & 15);
    const float* xr0 = x + (size_t)row0 * KDIM + wave * 512 + 8 * (lane >> 4);
    const float* xr1 = xr0 + (size_t)16 * KDIM;
    const uint4* pb = packed + (wave * NSW) * (2 * 64);

    f32x4 acc00 = {0.f, 0.f, 0.f, 0.f};
    f32x4 acc01 = {0.f, 0.f, 0.f, 0.f};
    f32x4 acc10 = {0.f, 0.f, 0.f, 0.f};
    f32x4 acc11 = {0.f, 0.f, 0.f, 0.f};
    float ssqt0 = 0.f, ssqt1 = 0.f;

    #pragma unroll 2
    for (int s = 0; s < NSW; ++s) {
        const float4 p0 = *(const float4*)(xr0 + 32 * s);
        const float4 p1 = *(const float4*)(xr0 + 32 * s + 4);
        const float4 q0 = *(const float4*)(xr1 + 32 * s);
        const float4 q1 = *(const float4*)(xr1 + 32 * s + 4);
        BF b0, b1;
        b0.u4 = pb[(s * 2 + 0) * 64 + lane];
        b1.u4 = pb[(s * 2 + 1) * 64 + lane];

        ssqt0 = fmaf(p0.x, p0.x, ssqt0);
        ssqt0 = fmaf(p0.y, p0.y, ssqt0);
        ssqt0 = fmaf(p0.z, p0.z, ssqt0);
        ssqt0 = fmaf(p0.w, p0.w, ssqt0);
        ssqt0 = fmaf(p1.x, p1.x, ssqt0);
        ssqt0 = fmaf(p1.y, p1.y, ssqt0);
        ssqt0 = fmaf(p1.z, p1.z, ssqt0);
        ssqt0 = fmaf(p1.w, p1.w, ssqt0);
        ssqt1 = fmaf(q0.x, q0.x, ssqt1);
        ssqt1 = fmaf(q0.y, q0.y, ssqt1);
        ssqt1 = fmaf(q0.z, q0.z, ssqt1);
        ssqt1 = fmaf(q0.w, q0.w, ssqt1);
        ssqt1 = fmaf(q1.x, q1.x, ssqt1);
        ssqt1 = fmaf(q1.y, q1.y, ssqt1);
        ssqt1 = fmaf(q1.z, q1.z, ssqt1);
        ssqt1 = fmaf(q1.w, q1.w, ssqt1);

        BF af0, af1;
        af0.u4.x = cvt_pk_bf16(p0.x, p0.y);
        af0.u4.y = cvt_pk_bf16(p0.z, p0.w);
        af0.u4.z = cvt_pk_bf16(p1.x, p1.y);
        af0.u4.w = cvt_pk_bf16(p1.z, p1.w);
        af1.u4.x = cvt_pk_bf16(q0.x, q0.y);
        af1.u4.y = cvt_pk_bf16(q0.z, q0.w);
        af1.u4.z = cvt_pk_bf16(q1.x, q1.y);
        af1.u4.w = cvt_pk_bf16(q1.z, q1.w);

        acc00 = __builtin_amdgcn_mfma_f32_16x16x32_bf16(af0.h, b0.h, acc00, 0, 0, 0);
        acc01 = __builtin_amdgcn_mfma_f32_16x16x32_bf16(af0.h, b1.h, acc01, 0, 0, 0);
        acc10 = __builtin_amdgcn_mfma_f32_16x16x32_bf16(af1.h, b0.h, acc10, 0, 0, 0);
        acc11 = __builtin_amdgcn_mfma_f32_16x16x32_bf16(af1.h, b1.h, acc11, 0, 0, 0);
    }

    // fold the 4 k-offset lane groups (same row across l>>4)
    ssqt0 += __shfl_xor(ssqt0, 16);
    ssqt0 += __shfl_xor(ssqt0, 32);
    ssqt1 += __shfl_xor(ssqt1, 16);
    ssqt1 += __shfl_xor(ssqt1, 32);

    // ---- dump per-wave partials: red[wave][tile][j(9)][lane] ----
    float* myred = red + wave * 1152;
    #pragma unroll
    for (int r = 0; r < 4; ++r) myred[r * 64 + lane] = acc00[r];
    #pragma unroll
    for (int r = 0; r < 4; ++r) myred[(4 + r) * 64 + lane] = acc01[r];
    myred[8 * 64 + lane] = ssqt0;
    #pragma unroll
    for (int r = 0; r < 4; ++r) myred[576 + r * 64 + lane] = acc10[r];
    #pragma unroll
    for (int r = 0; r < 4; ++r) myred[576 + (4 + r) * 64 + lane] = acc11[r];
    myred[576 + 8 * 64 + lane] = ssqt1;
    __syncthreads();

    // ---- reduce 8 wave-slices into slot 0 (1152 sums, 512 threads) ----
    for (int i = t; i < 1152; i += 512) {
        float s = red[i];
        #pragma unroll
        for (int q = 1; q < 8; ++q)
            s += red[q * 1152 + i];
        red[i] = s;
    }
    __syncthreads();

    // ---- epilogue: 32 rows x 16 cells = all 512 threads ----
    // value(local row lr, col c) = red[tile*576 + jslot*64 + li],
    //   jslot = (lr&3) + (c<16 ? 0 : 4), li = (c&15) + 16*(lr>>2).
    {
        const int rr   = t >> 4;          // block row 0..31
        const int cell = t & 15;          // res cell i*4+jc
        const int tile = rr >> 4;
        const int lr   = rr & 15;
        const int gr   = g * BM + rr;
        const float* rb = red + tile * 576;

        const float scale = rsqrtf(rb[8 * 64 + lr] * (1.0f / KDIM) + 1e-6f);
        const int li = 16 * (lr >> 2);
        const int j0 = lr & 3;

        if (cell < 4) {
            const float v = rb[j0 * 64 + li + cell];
            out[gr * 4 + cell] = sigmoidf_(fmaf(a_pre[0] * scale, v, b_pre[cell]));
        } else if (cell < 8) {
            const float v = rb[j0 * 64 + li + cell];
            out[32768 + gr * 4 + (cell - 4)] =
                2.f * sigmoidf_(fmaf(a_post[0] * scale, v, b_post[cell - 4]));
        }

        // res column 8+cell (acc*0 holds cols 0-15, acc*1 cols 16-31)
        const int col   = 8 + cell;
        const int jslot = j0 + (col < 16 ? 0 : 4);
        const float v   = rb[jslot * 64 + (col & 15) + li];
        float m = __expf(fmaf(a_res[0] * scale, v, b_res[cell]));

        for (int it = 0; it < 20; ++it) {
            float s = m + __shfl_xor(m, 1);       // row sum over jc
            s += __shfl_xor(s, 2);
            m /= s;
            float c = m + __shfl_xor(m, 4);       // col sum over i
            c += __shfl_xor(c, 8);
            m /= c;
        }
        out[65536 + gr * 16 + cell] = m;
    }
}

extern "C" void kernel_launch(void* const* d_in, const int* in_sizes, int n_in,
                              void* d_out, int out_size, void* d_ws, size_t ws_size,
                              hipStream_t stream) {
    const float* x      = (const float*)d_in[0];
    const float* rmsw   = (const float*)d_in[1];
    const float* ppre   = (const float*)d_in[2];
    const float* ppost  = (const float*)d_in[3];
    const float* pres   = (const float*)d_in[4];
    const float* b_pre  = (const float*)d_in[5];
    const float* b_post = (const float*)d_in[6];
    const float* b_res  = (const float*)d_in[7];
    const float* a_pre  = (const float*)d_in[8];
    const float* a_post = (const float*)d_in[9];
    const float* a_res  = (const float*)d_in[10];
    float* out = (float*)d_out;

    uint4* packed = (uint4*)d_ws;   // 256 KB
    hipLaunchKernelGGL(mhc_pack, dim3(128), dim3(128), 0, stream,
                       rmsw, ppre, ppost, pres, packed);
    hipLaunchKernelGGL(mhc_full, dim3(256), dim3(512), 0, stream,
                       x, packed, b_pre, b_post, b_res,
                       a_pre, a_post, a_res, out);
}

// Round 21
// 35.409 us; speedup vs baseline: 1.1357x; 1.0698x over previous
//
#include <hip/hip_runtime.h>
#include <math.h>

#define ROWS_TOTAL 8192
#define KDIM 4096
#define NJ 25
#define BM 32            // rows per block: two 16-row tiles per wave
#define NSW 16           // K-steps of 32 per wave (8 waves x 512 k)

typedef __attribute__((ext_vector_type(8))) short bf16x8;
typedef __attribute__((ext_vector_type(4))) float f32x4;

// gfx950 packed f32->bf16 (RNE); asm cvt_pk beat pure-C f2bf here (R13 vs R15).
__device__ __forceinline__ unsigned cvt_pk_bf16(float lo, float hi) {
    unsigned r;
    asm("v_cvt_pk_bf16_f32 %0, %1, %2" : "=v"(r) : "v"(lo), "v"(hi));
    return r;
}

union BF { uint4 u4; bf16x8 h; };

__device__ __forceinline__ float sigmoidf_(float z) {
    return 1.f / (1.f + __expf(-z));
}

// async global->LDS, 16B/lane, dest = base + lane*16 (linear, wave-uniform base)
#define GLL16(gsrc, ldst) \
  __builtin_amdgcn_global_load_lds( \
      (const __attribute__((address_space(1))) void*)(gsrc), \
      (__attribute__((address_space(3))) void*)(ldst), 16, 0, 0)

// ------------------------------------------------------------------
// Kernel 0: pack B = (rmsw * phi) into MFMA-fragment order, bf16.
// (unchanged from R18)
// ------------------------------------------------------------------
__global__ __launch_bounds__(128) void mhc_pack(
    const float* __restrict__ rmsw,
    const float* __restrict__ phi_pre,
    const float* __restrict__ phi_post,
    const float* __restrict__ phi_res,
    uint4* __restrict__ packed)
{
    const int fid = blockIdx.x * 128 + threadIdx.x;   // 0..16383
    const int s   = fid >> 7;
    const int n   = (fid >> 6) & 1;
    const int ln  = fid & 63;
    const int col = n * 16 + (ln & 15);
    const int kl  = s * 32 + 8 * (ln >> 4);
    float v[8];
    #pragma unroll
    for (int j = 0; j < 8; ++j) {
        const int k = kl + j;
        float vv = 0.f;
        if (col < 4)       vv = rmsw[k] * phi_pre[k * 4 + col];
        else if (col < 8)  vv = rmsw[k] * phi_post[k * 4 + (col - 4)];
        else if (col < 24) vv = rmsw[k] * phi_res[k * 16 + (col - 8)];
        v[j] = vv;
    }
    uint4 pk;
    pk.x = cvt_pk_bf16(v[0], v[1]);
    pk.y = cvt_pk_bf16(v[2], v[3]);
    pk.z = cvt_pk_bf16(v[4], v[5]);
    pk.w = cvt_pk_bf16(v[6], v[7]);
    packed[fid] = pk;
}

// ------------------------------------------------------------------
// Kernel 1: full-K projection + epilogue, ASYNC-STAGED x.
// 256 blocks x 512 thr; wave w owns k in [512w, 512w+512) for 32 rows.
// x staged via global_load_lds into a WAVE-PRIVATE 2x4KB double buffer
// (no __syncthreads in the K-loop; per-wave counted s_waitcnt vmcnt(6)
// with 4 gll + 2 B-prefetch issued per iteration between asm fences).
// Outstanding bytes/CU: 16 waves x 4KB = 64KB >> 20KB latency-BW need
// (direct loads capped at ~3KB -> the measured 1.9 TB/s HBM).
// Source-lane XOR swizzle (piece ^= row&7): gll reads 8 rows x 128B
// contiguous per instr; ds_read_b128 frag reads land ~2-way on banks.
// LDS 64KB (reduce region overlaid) -> 2 blocks/CU at VGPR<=128.
// ------------------------------------------------------------------
__global__ __launch_bounds__(512) void mhc_full(
    const float* __restrict__ x,
    const uint4* __restrict__ packed,
    const float* __restrict__ b_pre,
    const float* __restrict__ b_post,
    const float* __restrict__ b_res,
    const float* __restrict__ a_pre,
    const float* __restrict__ a_post,
    const float* __restrict__ a_res,
    float* __restrict__ out)
{
    __shared__ __align__(16) float xbuf[8][2][1024];   // 64KB; overlaid by red[]
    float* const red = &xbuf[0][0][0];

    const int t    = threadIdx.x;
    const int wave = t >> 6;               // 0..7 = k-slice (512 k each)
    const int lane = t & 63;
    const int g    = blockIdx.x;           // row group 0..255

    const int k0 = wave * 512;
    const uint4* pb = packed + (wave * NSW) * (2 * 64);

    // staging roles: lane -> (row-in-octet, swizzled 16B piece)
    const int srow = lane >> 3;            // 0..7
    const int sp   = (lane & 7) ^ srow;    // piece ^ row&7 (involution)
    const float* xsrc = x + (size_t)(g * BM + srow) * KDIM + k0 + sp * 4;

    // LDS float offset of (local row r, piece p) within a chunk
    #define LDSOFF(r, p) (((r) >> 3) * 256 + ((r) & 7) * 32 + ((((p) ^ ((r) & 7))) << 2))

    f32x4 acc00 = {0.f, 0.f, 0.f, 0.f};
    f32x4 acc01 = {0.f, 0.f, 0.f, 0.f};
    f32x4 acc10 = {0.f, 0.f, 0.f, 0.f};
    f32x4 acc11 = {0.f, 0.f, 0.f, 0.f};
    float ssqt0 = 0.f, ssqt1 = 0.f;

    const int r0 = lane & 15;              // tile0 local row
    const int p0 = 2 * (lane >> 4);        // first 16B piece of this lane's k-chunk

    // ---- prologue: stage step 0, load B(0) ----
    #pragma unroll
    for (int o = 0; o < 4; ++o)
        GLL16(xsrc + (size_t)o * 8 * KDIM, &xbuf[wave][0][o * 256]);
    BF b0, b1;
    b0.u4 = pb[0 * 64 + lane];
    b1.u4 = pb[1 * 64 + lane];

    #pragma unroll 1
    for (int s = 0; s < NSW; ++s) {
        BF bn0, bn1;
        if (s < NSW - 1) {
            // issue next step's stage + B prefetch (6 VMEM ops)
            const float* sb = xsrc + (s + 1) * 32;
            #pragma unroll
            for (int o = 0; o < 4; ++o)
                GLL16(sb + (size_t)o * 8 * KDIM, &xbuf[wave][(s + 1) & 1][o * 256]);
            bn0.u4 = pb[((s + 1) * 2 + 0) * 64 + lane];
            bn1.u4 = pb[((s + 1) * 2 + 1) * 64 + lane];
            asm volatile("s_waitcnt vmcnt(6)" ::: "memory");   // step s's glls drained
        } else {
            asm volatile("s_waitcnt vmcnt(0)" ::: "memory");
        }
        __builtin_amdgcn_sched_barrier(0);   // rule 18: pin reads after the wait

        const float* xb = &xbuf[wave][s & 1][0];
        const float4 a0 = *(const float4*)(xb + LDSOFF(r0,      p0));
        const float4 a1 = *(const float4*)(xb + LDSOFF(r0,      p0 + 1));
        const float4 q0 = *(const float4*)(xb + LDSOFF(r0 + 16, p0));
        const float4 q1 = *(const float4*)(xb + LDSOFF(r0 + 16, p0 + 1));

        ssqt0 = fmaf(a0.x, a0.x, ssqt0);
        ssqt0 = fmaf(a0.y, a0.y, ssqt0);
        ssqt0 = fmaf(a0.z, a0.z, ssqt0);
        ssqt0 = fmaf(a0.w, a0.w, ssqt0);
        ssqt0 = fmaf(a1.x, a1.x, ssqt0);
        ssqt0 = fmaf(a1.y, a1.y, ssqt0);
        ssqt0 = fmaf(a1.z, a1.z, ssqt0);
        ssqt0 = fmaf(a1.w, a1.w, ssqt0);
        ssqt1 = fmaf(q0.x, q0.x, ssqt1);
        ssqt1 = fmaf(q0.y, q0.y, ssqt1);
        ssqt1 = fmaf(q0.z, q0.z, ssqt1);
        ssqt1 = fmaf(q0.w, q0.w, ssqt1);
        ssqt1 = fmaf(q1.x, q1.x, ssqt1);
        ssqt1 = fmaf(q1.y, q1.y, ssqt1);
        ssqt1 = fmaf(q1.z, q1.z, ssqt1);
        ssqt1 = fmaf(q1.w, q1.w, ssqt1);

        BF af0, af1;
        af0.u4.x = cvt_pk_bf16(a0.x, a0.y);
        af0.u4.y = cvt_pk_bf16(a0.z, a0.w);
        af0.u4.z = cvt_pk_bf16(a1.x, a1.y);
        af0.u4.w = cvt_pk_bf16(a1.z, a1.w);
        af1.u4.x = cvt_pk_bf16(q0.x, q0.y);
        af1.u4.y = cvt_pk_bf16(q0.z, q0.w);
        af1.u4.z = cvt_pk_bf16(q1.x, q1.y);
        af1.u4.w = cvt_pk_bf16(q1.z, q1.w);

        acc00 = __builtin_amdgcn_mfma_f32_16x16x32_bf16(af0.h, b0.h, acc00, 0, 0, 0);
        acc01 = __builtin_amdgcn_mfma_f32_16x16x32_bf16(af0.h, b1.h, acc01, 0, 0, 0);
        acc10 = __builtin_amdgcn_mfma_f32_16x16x32_bf16(af1.h, b0.h, acc10, 0, 0, 0);
        acc11 = __builtin_amdgcn_mfma_f32_16x16x32_bf16(af1.h, b1.h, acc11, 0, 0, 0);

        b0 = bn0;
        b1 = bn1;
    }

    // fold the 4 k-offset lane groups (same row across l>>4)
    ssqt0 += __shfl_xor(ssqt0, 16);
    ssqt0 += __shfl_xor(ssqt0, 32);
    ssqt1 += __shfl_xor(ssqt1, 16);
    ssqt1 += __shfl_xor(ssqt1, 32);

    // all waves done reading xbuf before red[] overlays it
    __syncthreads();

    // ---- dump per-wave partials: red[wave][tile][j(9)][lane] ----
    float* myred = red + wave * 1152;
    #pragma unroll
    for (int r = 0; r < 4; ++r) myred[r * 64 + lane] = acc00[r];
    #pragma unroll
    for (int r = 0; r < 4; ++r) myred[(4 + r) * 64 + lane] = acc01[r];
    myred[8 * 64 + lane] = ssqt0;
    #pragma unroll
    for (int r = 0; r < 4; ++r) myred[576 + r * 64 + lane] = acc10[r];
    #pragma unroll
    for (int r = 0; r < 4; ++r) myred[576 + (4 + r) * 64 + lane] = acc11[r];
    myred[576 + 8 * 64 + lane] = ssqt1;
    __syncthreads();

    // ---- reduce 8 wave-slices into slot 0 (1152 sums, 512 threads) ----
    for (int i = t; i < 1152; i += 512) {
        float s = red[i];
        #pragma unroll
        for (int q = 1; q < 8; ++q)
            s += red[q * 1152 + i];
        red[i] = s;
    }
    __syncthreads();

    // ---- epilogue: 32 rows x 16 cells = all 512 threads ----
    {
        const int rr   = t >> 4;          // block row 0..31
        const int cell = t & 15;          // res cell i*4+jc
        const int tile = rr >> 4;
        const int lr   = rr & 15;
        const int gr   = g * BM + rr;
        const float* rb = red + tile * 576;

        const float scale = rsqrtf(rb[8 * 64 + lr] * (1.0f / KDIM) + 1e-6f);
        const int li = 16 * (lr >> 2);
        const int j0 = lr & 3;

        if (cell < 4) {
            const float v = rb[j0 * 64 + li + cell];
            out[gr * 4 + cell] = sigmoidf_(fmaf(a_pre[0] * scale, v, b_pre[cell]));
        } else if (cell < 8) {
            const float v = rb[j0 * 64 + li + cell];
            out[32768 + gr * 4 + (cell - 4)] =
                2.f * sigmoidf_(fmaf(a_post[0] * scale, v, b_post[cell - 4]));
        }

        // res column 8+cell (acc*0 holds cols 0-15, acc*1 cols 16-31)
        const int col   = 8 + cell;
        const int jslot = j0 + (col < 16 ? 0 : 4);
        const float v   = rb[jslot * 64 + (col & 15) + li];
        float m = __expf(fmaf(a_res[0] * scale, v, b_res[cell]));

        for (int it = 0; it < 20; ++it) {
            float s = m + __shfl_xor(m, 1);       // row sum over jc
            s += __shfl_xor(s, 2);
            m /= s;
            float c = m + __shfl_xor(m, 4);       // col sum over i
            c += __shfl_xor(c, 8);
            m /= c;
        }
        out[65536 + gr * 16 + cell] = m;
    }
}

extern "C" void kernel_launch(void* const* d_in, const int* in_sizes, int n_in,
                              void* d_out, int out_size, void* d_ws, size_t ws_size,
                              hipStream_t stream) {
    const float* x      = (const float*)d_in[0];
    const float* rmsw   = (const float*)d_in[1];
    const float* ppre   = (const float*)d_in[2];
    const float* ppost  = (const float*)d_in[3];
    const float* pres   = (const float*)d_in[4];
    const float* b_pre  = (const float*)d_in[5];
    const float* b_post = (const float*)d_in[6];
    const float* b_res  = (const float*)d_in[7];
    const float* a_pre  = (const float*)d_in[8];
    const float* a_post = (const float*)d_in[9];
    const float* a_res  = (const float*)d_in[10];
    float* out = (float*)d_out;

    uint4* packed = (uint4*)d_ws;   // 256 KB
    hipLaunchKernelGGL(mhc_pack, dim3(128), dim3(128), 0, stream,
                       rmsw, ppre, ppost, pres, packed);
    hipLaunchKernelGGL(mhc_full, dim3(256), dim3(512), 0, stream,
                       x, packed, b_pre, b_post, b_res,
                       a_pre, a_post, a_res, out);
}